// Round 5
// baseline (428.516 us; speedup 1.0000x reference)
//
#include <hip/hip_runtime.h>
#include <hip/hip_bf16.h>
#include <hip/hip_fp16.h>

#define B_ 2
#define S_ 2048
#define D_ 2048
#define H_ 8
#define KV_ 2
#define HD_ 256
#define WINDOW_ 512
#define EPS_ 1e-6f
#define MASKV_ -30000.0f

typedef _Float16 f16;
typedef _Float16 half8 __attribute__((ext_vector_type(8)));
typedef _Float16 half2v __attribute__((ext_vector_type(2)));
typedef _Float16 half4v __attribute__((ext_vector_type(4)));
typedef float floatx4 __attribute__((ext_vector_type(4)));

#define GLOAD_LDS16(g, l)                                                        \
    __builtin_amdgcn_global_load_lds(                                            \
        (const __attribute__((address_space(1))) unsigned int*)(g),              \
        (__attribute__((address_space(3))) unsigned int*)(l), 16, 0, 0)

// ---------------------------------------------------------------------------
// prep: fp32->fp16 convert of x  +  all 4 weight transposes, one dispatch.
// ---------------------------------------------------------------------------
__global__ __launch_bounds__(256) void prep(const float* __restrict__ x,
                                            const float* __restrict__ wq,
                                            const float* __restrict__ wk,
                                            const float* __restrict__ wv,
                                            const float* __restrict__ wo,
                                            f16* __restrict__ xh,
                                            f16* __restrict__ BT,
                                            f16* __restrict__ woT) {
    int bid = blockIdx.x;
    const int t = threadIdx.x;
    if (bid < 8192) {
        const int i = bid * 256 + t;
        float4 v = ((const float4*)x)[i];
        half4v hv = {(f16)v.x, (f16)v.y, (f16)v.z, (f16)v.w};
        ((half4v*)xh)[i] = hv;
        return;
    }
    bid -= 8192;
    const float* src;
    f16* dst;
    int C, bx, by;
    if (bid < 4096) {
        src = wq; dst = BT; C = 2048; bx = bid & 63; by = bid >> 6;
    } else if (bid < 5120) {
        const int b2 = bid - 4096;
        src = wk; dst = BT + (size_t)2048 * 2048; C = 512; bx = b2 & 15; by = b2 >> 4;
    } else if (bid < 6144) {
        const int b2 = bid - 5120;
        src = wv; dst = BT + (size_t)2560 * 2048; C = 512; bx = b2 & 15; by = b2 >> 4;
    } else {
        const int b2 = bid - 6144;
        src = wo; dst = woT; C = 2048; bx = b2 & 63; by = b2 >> 6;
    }
    __shared__ float tile[32][33];
    const int tx = t & 31, ty = t >> 5;  // 32 x 8
    const int c0 = bx * 32, r0 = by * 32;
#pragma unroll
    for (int i = 0; i < 4; ++i)
        tile[ty + i * 8][tx] = src[(size_t)(r0 + ty + i * 8) * C + c0 + tx];
    __syncthreads();
#pragma unroll
    for (int i = 0; i < 4; ++i)
        dst[(size_t)(c0 + ty + i * 8) * 2048 + r0 + tx] = (f16)tile[tx][ty + i * 8];
}

// ---------------------------------------------------------------------------
// fp16 MFMA GEMM: C[M,N] = A[M,K] @ BT[N,K]^T.  128x128 tile, BK=32,
// 4 waves (2x2 of 64x64), 16x16x32 MFMA, global_load_lds staging with
// XOR group swizzle to keep LDS fragment reads 2-way (free).
// ---------------------------------------------------------------------------
template <typename OutT>
__global__ __launch_bounds__(256) void gemm_f16(const f16* __restrict__ A,
                                                const f16* __restrict__ BT,
                                                OutT* __restrict__ C,
                                                int M, int N, int K) {
    __shared__ __align__(16) f16 sA[128 * 32];
    __shared__ __align__(16) f16 sB[128 * 32];

    const int t = threadIdx.x;
    const int lane = t & 63;
    const int w = t >> 6;
    const int i16 = lane & 15, q4 = lane >> 4;
    const int m0 = blockIdx.y * 128, n0 = blockIdx.x * 128;
    const int mw = (w & 1) * 64, nw = (w >> 1) * 64;

    floatx4 acc[16];
#pragma unroll
    for (int i = 0; i < 16; ++i) acc[i] = (floatx4){0.f, 0.f, 0.f, 0.f};

    const int srow = w * 32 + (lane >> 2);
    const int sgp = lane & 3;

    for (int k0 = 0; k0 < K; k0 += 32) {
#pragma unroll
        for (int c = 0; c < 2; ++c) {
            const int chunk = w * 2 + c;
            const int row = srow + c * 16;
            const int g = (sgp - (row >> 1)) & 3;
            GLOAD_LDS16(A + (size_t)(m0 + row) * K + k0 + g * 8,
                        sA + chunk * 512 + lane * 8);
            GLOAD_LDS16(BT + (size_t)(n0 + row) * K + k0 + g * 8,
                        sB + chunk * 512 + lane * 8);
        }
        __syncthreads();

        half8 af[4], bf[4];
#pragma unroll
        for (int mi = 0; mi < 4; ++mi) {
            const int row = mw + mi * 16 + i16;
            const int gp = (q4 + (row >> 1)) & 3;
            af[mi] = *(const half8*)(sA + row * 32 + gp * 8);
        }
#pragma unroll
        for (int ni = 0; ni < 4; ++ni) {
            const int row = nw + ni * 16 + i16;
            const int gp = (q4 + (row >> 1)) & 3;
            bf[ni] = *(const half8*)(sB + row * 32 + gp * 8);
        }
#pragma unroll
        for (int mi = 0; mi < 4; ++mi)
#pragma unroll
            for (int ni = 0; ni < 4; ++ni)
                acc[mi * 4 + ni] = __builtin_amdgcn_mfma_f32_16x16x32_f16(
                    af[mi], bf[ni], acc[mi * 4 + ni], 0, 0, 0);
        __syncthreads();
    }

#pragma unroll
    for (int mi = 0; mi < 4; ++mi)
#pragma unroll
        for (int ni = 0; ni < 4; ++ni)
#pragma unroll
            for (int r = 0; r < 4; ++r) {
                const int row = m0 + mw + mi * 16 + q4 * 4 + r;
                const int col = n0 + nw + ni * 16 + i16;
                C[(size_t)row * N + col] = (OutT)acc[mi * 4 + ni][r];
            }
}

// ---------------------------------------------------------------------------
// Fused norm/rope kernel. Blocks [0, NRB): Q in-place + K -> Kh (one wave
// per 256-elem head row). Blocks [NRB, NRB+128): V norm + coalesced
// transpose to Vt[(b*KV+kv)][d][s] via a padded LDS tile (no 2B scatters).
// ---------------------------------------------------------------------------
#define NRB_ ((B_ * S_ * (H_ + KV_)) / 4)  // 10240 rope blocks (4 waves each)

__global__ __launch_bounds__(256) void norm_rope_f16(
    f16* __restrict__ QKVh, f16* __restrict__ Kh, f16* __restrict__ Vt,
    const float* __restrict__ cosb, const float* __restrict__ sinb,
    const float* __restrict__ qw, const float* __restrict__ kw) {
    __shared__ f16 vt[64][266];  // 34 KB, pad 266 -> 2-way banks both phases

    const int w = threadIdx.x >> 6, lane = threadIdx.x & 63;

    if (blockIdx.x < NRB_) {
        const int wid = blockIdx.x * 4 + w;
        const int nq = B_ * S_ * H_;
        const int d0 = lane * 2;

        if (wid < nq) {
            const int b = wid / (S_ * H_);
            const int r = wid % (S_ * H_);
            const int s = r / H_, h = r % H_;
            f16* p = QKVh + (size_t)(b * S_ + s) * 3072 + h * HD_;
            half2v lo = *(const half2v*)(p + d0);
            half2v hi = *(const half2v*)(p + 128 + d0);
            float x0 = (float)lo[0], x1 = (float)lo[1], x2 = (float)hi[0], x3 = (float)hi[1];
            float ss = x0 * x0 + x1 * x1 + x2 * x2 + x3 * x3;
#pragma unroll
            for (int off = 32; off >= 1; off >>= 1) ss += __shfl_xor(ss, off);
            const float inv = rsqrtf(ss * (1.0f / HD_) + EPS_);
            float2 wlo = *(const float2*)(qw + d0), whi = *(const float2*)(qw + 128 + d0);
            float y0 = x0 * inv * wlo.x, y1 = x1 * inv * wlo.y;
            float y2 = x2 * inv * whi.x, y3 = x3 * inv * whi.y;
            const float* cb = cosb + (size_t)(b * S_ + s) * HD_;
            const float* sb = sinb + (size_t)(b * S_ + s) * HD_;
            float2 clo = *(const float2*)(cb + d0), chi = *(const float2*)(cb + 128 + d0);
            float2 slo = *(const float2*)(sb + d0), shi = *(const float2*)(sb + 128 + d0);
            half2v olo = {(f16)(y0 * clo.x - y2 * slo.x), (f16)(y1 * clo.y - y3 * slo.y)};
            half2v ohi = {(f16)(y2 * chi.x + y0 * shi.x), (f16)(y3 * chi.y + y1 * shi.y)};
            *(half2v*)(p + d0) = olo;
            *(half2v*)(p + 128 + d0) = ohi;
        } else {
            const int idx = wid - nq;
            const int b = idx / (S_ * KV_);
            const int r = idx % (S_ * KV_);
            const int s = r / KV_, kv = r % KV_;
            const f16* p = QKVh + (size_t)(b * S_ + s) * 3072 + 2048 + kv * HD_;
            half2v lo = *(const half2v*)(p + d0);
            half2v hi = *(const half2v*)(p + 128 + d0);
            float x0 = (float)lo[0], x1 = (float)lo[1], x2 = (float)hi[0], x3 = (float)hi[1];
            float ss = x0 * x0 + x1 * x1 + x2 * x2 + x3 * x3;
#pragma unroll
            for (int off = 32; off >= 1; off >>= 1) ss += __shfl_xor(ss, off);
            const float inv = rsqrtf(ss * (1.0f / HD_) + EPS_);
            float2 wlo = *(const float2*)(kw + d0), whi = *(const float2*)(kw + 128 + d0);
            float y0 = x0 * inv * wlo.x, y1 = x1 * inv * wlo.y;
            float y2 = x2 * inv * whi.x, y3 = x3 * inv * whi.y;
            const float* cb = cosb + (size_t)(b * S_ + s) * HD_;
            const float* sb = sinb + (size_t)(b * S_ + s) * HD_;
            float2 clo = *(const float2*)(cb + d0), chi = *(const float2*)(cb + 128 + d0);
            float2 slo = *(const float2*)(sb + d0), shi = *(const float2*)(sb + 128 + d0);
            half2v olo = {(f16)(y0 * clo.x - y2 * slo.x), (f16)(y1 * clo.y - y3 * slo.y)};
            half2v ohi = {(f16)(y2 * chi.x + y0 * shi.x), (f16)(y3 * chi.y + y1 * shi.y)};
            f16* d = Kh + ((size_t)(b * KV_ + kv) * S_ + s) * HD_;
            *(half2v*)(d + d0) = olo;
            *(half2v*)(d + 128 + d0) = ohi;
        }
        return;
    }

    // ---- V path: one block per (b, kv, 64-row s-tile) ----
    const int vb = blockIdx.x - NRB_;          // 0..127
    const int s0 = (vb & 31) * 64;
    const int kv = (vb >> 5) & 1;
    const int b  = vb >> 6;

    // phase 1: normalize 16 rows per wave into LDS tile [s_local][d]
    for (int r = 0; r < 16; ++r) {
        const int sl = w * 16 + r;
        const f16* p = QKVh + (size_t)(b * S_ + s0 + sl) * 3072 + 2560 + kv * HD_;
        const int d0 = lane * 2;
        half2v lo = *(const half2v*)(p + d0);
        half2v hi = *(const half2v*)(p + 128 + d0);
        float x0 = (float)lo[0], x1 = (float)lo[1], x2 = (float)hi[0], x3 = (float)hi[1];
        float ss = x0 * x0 + x1 * x1 + x2 * x2 + x3 * x3;
#pragma unroll
        for (int off = 32; off >= 1; off >>= 1) ss += __shfl_xor(ss, off);
        const float inv = rsqrtf(ss * (1.0f / HD_) + EPS_);
        half2v olo = {(f16)(x0 * inv), (f16)(x1 * inv)};
        half2v ohi = {(f16)(x2 * inv), (f16)(x3 * inv)};
        *(half2v*)&vt[sl][d0] = olo;
        *(half2v*)&vt[sl][128 + d0] = ohi;
    }
    __syncthreads();
    // phase 2: coalesced transposed write: wave w handles d-rows 64w..64w+63
    f16* dst = Vt + (size_t)(b * KV_ + kv) * HD_ * S_;
    for (int i = 0; i < 64; ++i) {
        const int dd = w * 64 + i;
        dst[(size_t)dd * S_ + s0 + lane] = vt[lane][dd];
    }
}

// ---------------------------------------------------------------------------
// MFMA flash attention v3. Block = (qt, h, b): 128 queries, 8 waves x 16 q.
// Single-buffered 64-key K/V tiles (74 KB LDS total) + VGPR cap 128 ->
// 2 blocks/CU (4 waves/SIMD): cross-block overlap hides barrier drains.
// P scratch halved: write/consume P in two 32-key halves (wave-local).
// ---------------------------------------------------------------------------
__global__ __launch_bounds__(512, 4) void attn_mfma(const f16* __restrict__ QKVh,
                                                    const f16* __restrict__ Kh,
                                                    const f16* __restrict__ Vt,
                                                    f16* __restrict__ attnh) {
    __shared__ __align__(16) f16 sK[64 * 256];   // 32 KB [key][dim], XOR swizzle
    __shared__ __align__(16) f16 sV[256 * 64];   // 32 KB [dim][key], XOR swizzle
    __shared__ __align__(16) f16 sP[8][16 * 40]; // 10 KB per-wave P halves

    const int qt = blockIdx.x, h = blockIdx.y, b = blockIdx.z;
    const int kvh = h / (H_ / KV_);
    const int t = threadIdx.x, lane = t & 63, w = t >> 6;
    const int i16 = lane & 15, q4 = lane >> 4;

    // Q fragments (A-layout): query row = i16, dims k = kk*32 + q4*8 + j
    const int qrow = qt * 128 + w * 16 + i16;
    const f16* qbase = QKVh + (size_t)(b * S_ + qrow) * 3072 + h * HD_ + q4 * 8;
    half8 qf[8];
#pragma unroll
    for (int kk = 0; kk < 8; ++kk) qf[kk] = *(const half8*)(qbase + kk * 32);

    floatx4 o[16];
#pragma unroll
    for (int i = 0; i < 16; ++i) o[i] = (floatx4){0.f, 0.f, 0.f, 0.f};
    float mrow[4] = {-1e30f, -1e30f, -1e30f, -1e30f};
    float lrow[4] = {0.f, 0.f, 0.f, 0.f};

    const size_t kbase = (size_t)(b * KV_ + kvh) * S_ * HD_;
    const size_t vbase = (size_t)(b * KV_ + kvh) * HD_ * S_;
    const int srow0 = qt * 128 + w * 16 + q4 * 4;

    const int kt_lo = (2 * qt - 8) > 0 ? (2 * qt - 8) : 0;
    const int kt_hi = 2 * qt + 1;
    const int s_lo_w = qt * 128 + w * 16;
    int ktw_lo = (s_lo_w - (WINDOW_ - 1)) >> 6;
    if (ktw_lo < kt_lo) ktw_lo = kt_lo;
    const int ktw_hi = (s_lo_w + 15) >> 6;

    for (int kt = kt_lo; kt <= kt_hi; ++kt) {
        // ---- stage K+V (64 KB / 8 waves = 4+4 instrs per wave) ----
#pragma unroll
        for (int c = 0; c < 4; ++c) {
            const int chunk = w * 4 + c;
            const int keyl = chunk * 2 + (lane >> 5);
            const int g = (lane & 31) ^ (keyl & 31);
            GLOAD_LDS16(Kh + kbase + (size_t)(kt * 64 + keyl) * HD_ + g * 8,
                        sK + chunk * 512 + lane * 8);
            const int diml = chunk * 8 + (lane >> 3);
            const int g2 = (lane & 7) ^ (diml & 7);
            GLOAD_LDS16(Vt + vbase + (size_t)diml * S_ + kt * 64 + g2 * 8,
                        sV + chunk * 512 + lane * 8);
        }
        __syncthreads();  // implicit vmcnt(0): staged data visible

        if (kt >= ktw_lo && kt <= ktw_hi) {
            // ---- QK^T (nt outer to shrink live range) ----
            floatx4 sc[4];
#pragma unroll
            for (int nt = 0; nt < 4; ++nt) {
                floatx4 a = (floatx4){0.f, 0.f, 0.f, 0.f};
                const int keyl = nt * 16 + i16;
#pragma unroll
                for (int ks = 0; ks < 8; ++ks) {
                    const int gp = (ks * 4 + q4) ^ (keyl & 31);
                    half8 kf = *(const half8*)(sK + keyl * 256 + gp * 8);
                    a = __builtin_amdgcn_mfma_f32_16x16x32_f16(qf[ks], kf, a, 0, 0, 0);
                }
                sc[nt] = a;
            }

            // ---- mask + online softmax ----
#pragma unroll
            for (int r = 0; r < 4; ++r) {
                const int s = srow0 + r;
                float mx = -1e30f;
#pragma unroll
                for (int nt = 0; nt < 4; ++nt) {
                    const int j = kt * 64 + nt * 16 + i16;
                    const bool valid = (j <= s) && (s - j < WINDOW_);
                    const float v = valid ? sc[nt][r] : MASKV_;
                    sc[nt][r] = v;
                    mx = fmaxf(mx, v);
                }
#pragma unroll
                for (int off = 1; off < 16; off <<= 1) mx = fmaxf(mx, __shfl_xor(mx, off));
                const float mnew = fmaxf(mrow[r], mx);
                const float alpha = __expf(mrow[r] - mnew);
                mrow[r] = mnew;
                float rs = 0.f;
#pragma unroll
                for (int nt = 0; nt < 4; ++nt) {
                    const float p = __expf(sc[nt][r] - mnew);
                    sc[nt][r] = p;
                    rs += p;
                }
#pragma unroll
                for (int off = 1; off < 16; off <<= 1) rs += __shfl_xor(rs, off);
                lrow[r] = lrow[r] * alpha + rs;
#pragma unroll
                for (int nt2 = 0; nt2 < 16; ++nt2) o[nt2][r] *= alpha;
            }

            // ---- PV in two 32-key halves (wave-local P round-trip) ----
            f16* sPw = sP[w];
#pragma unroll
            for (int hf = 0; hf < 2; ++hf) {
#pragma unroll
                for (int nt = 0; nt < 2; ++nt)
#pragma unroll
                    for (int r = 0; r < 4; ++r)
                        sPw[(q4 * 4 + r) * 40 + nt * 16 + i16] = (f16)sc[hf * 2 + nt][r];
                asm volatile("s_waitcnt lgkmcnt(0)" ::: "memory");
                half8 pf = *(const half8*)(sPw + i16 * 40 + q4 * 8);
#pragma unroll
                for (int nt2 = 0; nt2 < 16; ++nt2) {
                    const int dim = nt2 * 16 + i16;
                    const int gp = (hf * 4 + q4) ^ (dim & 7);
                    half8 vf = *(const half8*)(sV + dim * 64 + gp * 8);
                    o[nt2] = __builtin_amdgcn_mfma_f32_16x16x32_f16(pf, vf, o[nt2], 0, 0, 0);
                }
            }
        }
        __syncthreads();  // all reads done before next stage overwrites
    }

    // ---- epilogue ----
    float inv[4];
#pragma unroll
    for (int r = 0; r < 4; ++r) inv[r] = 1.0f / lrow[r];
    f16* ob = attnh + (size_t)(b * S_ + qt * 128 + w * 16) * (H_ * HD_) + h * HD_;
#pragma unroll
    for (int nt2 = 0; nt2 < 16; ++nt2)
#pragma unroll
        for (int r = 0; r < 4; ++r)
            ob[(size_t)(q4 * 4 + r) * (H_ * HD_) + nt2 * 16 + i16] =
                (f16)(o[nt2][r] * inv[r]);
}

// ---------------------------------------------------------------------------
extern "C" void kernel_launch(void* const* d_in, const int* in_sizes, int n_in,
                              void* d_out, int out_size, void* d_ws, size_t ws_size,
                              hipStream_t stream) {
    const float* x    = (const float*)d_in[0];
    const float* cosb = (const float*)d_in[1];
    const float* sinb = (const float*)d_in[2];
    const float* wq = (const float*)d_in[4];
    const float* wk = (const float*)d_in[5];
    const float* wv = (const float*)d_in[6];
    const float* wo = (const float*)d_in[7];
    const float* qw = (const float*)d_in[8];
    const float* kw = (const float*)d_in[9];
    float* out = (float*)d_out;

    f16* ws = (f16*)d_ws;
    f16* xh    = ws;                       // 8388608 (aliased as attnh later)
    f16* BT    = xh + 8388608;             // 6291456  [3072][2048]
    f16* woT   = BT + 6291456;             // 4194304  [2048][2048]
    f16* QKVh  = woT + 4194304;            // 12582912 [4096][3072]
    f16* Kh    = QKVh + 12582912;          // 2097152
    f16* Vt    = Kh + 2097152;             // 2097152
    f16* attnh = xh;                       // alias: xh dead after QKV GEMM

    const int M = B_ * S_;  // 4096

    // 1) convert x + transpose all weights (one dispatch)
    prep<<<18432, 256, 0, stream>>>(x, wq, wk, wv, wo, xh, BT, woT);

    // 2) fused QKV projection: [4096][2048] @ [3072][2048]^T
    gemm_f16<f16><<<dim3(24, 32), 256, 0, stream>>>(xh, BT, QKVh, M, 3072, D_);

    // 3) RMSNorm + RoPE (Q,K) + V norm/coalesced-transpose (one dispatch)
    norm_rope_f16<<<NRB_ + 128, 256, 0, stream>>>(QKVh, Kh, Vt, cosb, sinb, qw, kw);

    // 4) flash attention (128-query tiles, 2 blocks/CU)
    attn_mfma<<<dim3(S_ / 128, H_, B_), 512, 0, stream>>>(QKVh, Kh, Vt, attnh);

    // 5) output projection (fp32 out)
    gemm_f16<float><<<dim3(16, 32), 256, 0, stream>>>(attnh, woT, out, M, D_, H_ * HD_);
}

// Round 6
// 339.132 us; speedup vs baseline: 1.2636x; 1.2636x over previous
//
#include <hip/hip_runtime.h>
#include <hip/hip_bf16.h>
#include <hip/hip_fp16.h>

#define B_ 2
#define S_ 2048
#define D_ 2048
#define H_ 8
#define KV_ 2
#define HD_ 256
#define WINDOW_ 512
#define EPS_ 1e-6f
#define MASKV_ -30000.0f

typedef _Float16 f16;
typedef _Float16 half8 __attribute__((ext_vector_type(8)));
typedef _Float16 half2v __attribute__((ext_vector_type(2)));
typedef _Float16 half4v __attribute__((ext_vector_type(4)));
typedef float floatx4 __attribute__((ext_vector_type(4)));

#define GLOAD_LDS16(g, l)                                                        \
    __builtin_amdgcn_global_load_lds(                                            \
        (const __attribute__((address_space(1))) unsigned int*)(g),              \
        (__attribute__((address_space(3))) unsigned int*)(l), 16, 0, 0)

// ---------------------------------------------------------------------------
// prep: fp32->fp16 convert of x  +  all 4 weight transposes, one dispatch.
// ---------------------------------------------------------------------------
__global__ __launch_bounds__(256) void prep(const float* __restrict__ x,
                                            const float* __restrict__ wq,
                                            const float* __restrict__ wk,
                                            const float* __restrict__ wv,
                                            const float* __restrict__ wo,
                                            f16* __restrict__ xh,
                                            f16* __restrict__ BT,
                                            f16* __restrict__ woT) {
    int bid = blockIdx.x;
    const int t = threadIdx.x;
    if (bid < 8192) {
        const int i = bid * 256 + t;
        float4 v = ((const float4*)x)[i];
        half4v hv = {(f16)v.x, (f16)v.y, (f16)v.z, (f16)v.w};
        ((half4v*)xh)[i] = hv;
        return;
    }
    bid -= 8192;
    const float* src;
    f16* dst;
    int C, bx, by;
    if (bid < 4096) {
        src = wq; dst = BT; C = 2048; bx = bid & 63; by = bid >> 6;
    } else if (bid < 5120) {
        const int b2 = bid - 4096;
        src = wk; dst = BT + (size_t)2048 * 2048; C = 512; bx = b2 & 15; by = b2 >> 4;
    } else if (bid < 6144) {
        const int b2 = bid - 5120;
        src = wv; dst = BT + (size_t)2560 * 2048; C = 512; bx = b2 & 15; by = b2 >> 4;
    } else {
        const int b2 = bid - 6144;
        src = wo; dst = woT; C = 2048; bx = b2 & 63; by = b2 >> 6;
    }
    __shared__ float tile[32][33];
    const int tx = t & 31, ty = t >> 5;  // 32 x 8
    const int c0 = bx * 32, r0 = by * 32;
#pragma unroll
    for (int i = 0; i < 4; ++i)
        tile[ty + i * 8][tx] = src[(size_t)(r0 + ty + i * 8) * C + c0 + tx];
    __syncthreads();
#pragma unroll
    for (int i = 0; i < 4; ++i)
        dst[(size_t)(c0 + ty + i * 8) * 2048 + r0 + tx] = (f16)tile[tx][ty + i * 8];
}

// ---------------------------------------------------------------------------
// fp16 MFMA GEMM: C[M,N] = A[M,K] @ BT[N,K]^T.  128x128 tile, BK=32,
// 4 waves (2x2 of 64x64), 16x16x32 MFMA, global_load_lds staging with
// XOR group swizzle to keep LDS fragment reads 2-way (free).
// ---------------------------------------------------------------------------
template <typename OutT>
__global__ __launch_bounds__(256) void gemm_f16(const f16* __restrict__ A,
                                                const f16* __restrict__ BT,
                                                OutT* __restrict__ C,
                                                int M, int N, int K) {
    __shared__ __align__(16) f16 sA[128 * 32];
    __shared__ __align__(16) f16 sB[128 * 32];

    const int t = threadIdx.x;
    const int lane = t & 63;
    const int w = t >> 6;
    const int i16 = lane & 15, q4 = lane >> 4;
    const int m0 = blockIdx.y * 128, n0 = blockIdx.x * 128;
    const int mw = (w & 1) * 64, nw = (w >> 1) * 64;

    floatx4 acc[16];
#pragma unroll
    for (int i = 0; i < 16; ++i) acc[i] = (floatx4){0.f, 0.f, 0.f, 0.f};

    const int srow = w * 32 + (lane >> 2);
    const int sgp = lane & 3;

    for (int k0 = 0; k0 < K; k0 += 32) {
#pragma unroll
        for (int c = 0; c < 2; ++c) {
            const int chunk = w * 2 + c;
            const int row = srow + c * 16;
            const int g = (sgp - (row >> 1)) & 3;
            GLOAD_LDS16(A + (size_t)(m0 + row) * K + k0 + g * 8,
                        sA + chunk * 512 + lane * 8);
            GLOAD_LDS16(BT + (size_t)(n0 + row) * K + k0 + g * 8,
                        sB + chunk * 512 + lane * 8);
        }
        __syncthreads();

        half8 af[4], bf[4];
#pragma unroll
        for (int mi = 0; mi < 4; ++mi) {
            const int row = mw + mi * 16 + i16;
            const int gp = (q4 + (row >> 1)) & 3;
            af[mi] = *(const half8*)(sA + row * 32 + gp * 8);
        }
#pragma unroll
        for (int ni = 0; ni < 4; ++ni) {
            const int row = nw + ni * 16 + i16;
            const int gp = (q4 + (row >> 1)) & 3;
            bf[ni] = *(const half8*)(sB + row * 32 + gp * 8);
        }
#pragma unroll
        for (int mi = 0; mi < 4; ++mi)
#pragma unroll
            for (int ni = 0; ni < 4; ++ni)
                acc[mi * 4 + ni] = __builtin_amdgcn_mfma_f32_16x16x32_f16(
                    af[mi], bf[ni], acc[mi * 4 + ni], 0, 0, 0);
        __syncthreads();
    }

#pragma unroll
    for (int mi = 0; mi < 4; ++mi)
#pragma unroll
        for (int ni = 0; ni < 4; ++ni)
#pragma unroll
            for (int r = 0; r < 4; ++r) {
                const int row = m0 + mw + mi * 16 + q4 * 4 + r;
                const int col = n0 + nw + ni * 16 + i16;
                C[(size_t)row * N + col] = (OutT)acc[mi * 4 + ni][r];
            }
}

// ---------------------------------------------------------------------------
// Fused norm/rope kernel. Blocks [0, NRB): Q in-place + K -> Kh (one wave
// per 256-elem head row). Blocks [NRB, NRB+128): V norm + coalesced
// transpose to Vt[(b*KV+kv)][d][s] via a padded LDS tile (no 2B scatters).
// ---------------------------------------------------------------------------
#define NRB_ ((B_ * S_ * (H_ + KV_)) / 4)  // 10240 rope blocks (4 waves each)

__global__ __launch_bounds__(256) void norm_rope_f16(
    f16* __restrict__ QKVh, f16* __restrict__ Kh, f16* __restrict__ Vt,
    const float* __restrict__ cosb, const float* __restrict__ sinb,
    const float* __restrict__ qw, const float* __restrict__ kw) {
    __shared__ f16 vt[64][266];  // 34 KB, pad 266 -> 2-way banks both phases

    const int w = threadIdx.x >> 6, lane = threadIdx.x & 63;

    if (blockIdx.x < NRB_) {
        const int wid = blockIdx.x * 4 + w;
        const int nq = B_ * S_ * H_;
        const int d0 = lane * 2;

        if (wid < nq) {
            const int b = wid / (S_ * H_);
            const int r = wid % (S_ * H_);
            const int s = r / H_, h = r % H_;
            f16* p = QKVh + (size_t)(b * S_ + s) * 3072 + h * HD_;
            half2v lo = *(const half2v*)(p + d0);
            half2v hi = *(const half2v*)(p + 128 + d0);
            float x0 = (float)lo[0], x1 = (float)lo[1], x2 = (float)hi[0], x3 = (float)hi[1];
            float ss = x0 * x0 + x1 * x1 + x2 * x2 + x3 * x3;
#pragma unroll
            for (int off = 32; off >= 1; off >>= 1) ss += __shfl_xor(ss, off);
            const float inv = rsqrtf(ss * (1.0f / HD_) + EPS_);
            float2 wlo = *(const float2*)(qw + d0), whi = *(const float2*)(qw + 128 + d0);
            float y0 = x0 * inv * wlo.x, y1 = x1 * inv * wlo.y;
            float y2 = x2 * inv * whi.x, y3 = x3 * inv * whi.y;
            const float* cb = cosb + (size_t)(b * S_ + s) * HD_;
            const float* sb = sinb + (size_t)(b * S_ + s) * HD_;
            float2 clo = *(const float2*)(cb + d0), chi = *(const float2*)(cb + 128 + d0);
            float2 slo = *(const float2*)(sb + d0), shi = *(const float2*)(sb + 128 + d0);
            half2v olo = {(f16)(y0 * clo.x - y2 * slo.x), (f16)(y1 * clo.y - y3 * slo.y)};
            half2v ohi = {(f16)(y2 * chi.x + y0 * shi.x), (f16)(y3 * chi.y + y1 * shi.y)};
            *(half2v*)(p + d0) = olo;
            *(half2v*)(p + 128 + d0) = ohi;
        } else {
            const int idx = wid - nq;
            const int b = idx / (S_ * KV_);
            const int r = idx % (S_ * KV_);
            const int s = r / KV_, kv = r % KV_;
            const f16* p = QKVh + (size_t)(b * S_ + s) * 3072 + 2048 + kv * HD_;
            half2v lo = *(const half2v*)(p + d0);
            half2v hi = *(const half2v*)(p + 128 + d0);
            float x0 = (float)lo[0], x1 = (float)lo[1], x2 = (float)hi[0], x3 = (float)hi[1];
            float ss = x0 * x0 + x1 * x1 + x2 * x2 + x3 * x3;
#pragma unroll
            for (int off = 32; off >= 1; off >>= 1) ss += __shfl_xor(ss, off);
            const float inv = rsqrtf(ss * (1.0f / HD_) + EPS_);
            float2 wlo = *(const float2*)(kw + d0), whi = *(const float2*)(kw + 128 + d0);
            float y0 = x0 * inv * wlo.x, y1 = x1 * inv * wlo.y;
            float y2 = x2 * inv * whi.x, y3 = x3 * inv * whi.y;
            const float* cb = cosb + (size_t)(b * S_ + s) * HD_;
            const float* sb = sinb + (size_t)(b * S_ + s) * HD_;
            float2 clo = *(const float2*)(cb + d0), chi = *(const float2*)(cb + 128 + d0);
            float2 slo = *(const float2*)(sb + d0), shi = *(const float2*)(sb + 128 + d0);
            half2v olo = {(f16)(y0 * clo.x - y2 * slo.x), (f16)(y1 * clo.y - y3 * slo.y)};
            half2v ohi = {(f16)(y2 * chi.x + y0 * shi.x), (f16)(y3 * chi.y + y1 * shi.y)};
            f16* d = Kh + ((size_t)(b * KV_ + kv) * S_ + s) * HD_;
            *(half2v*)(d + d0) = olo;
            *(half2v*)(d + 128 + d0) = ohi;
        }
        return;
    }

    // ---- V path: one block per (b, kv, 64-row s-tile) ----
    const int vb = blockIdx.x - NRB_;          // 0..127
    const int s0 = (vb & 31) * 64;
    const int kv = (vb >> 5) & 1;
    const int b  = vb >> 6;

    // phase 1: normalize 16 rows per wave into LDS tile [s_local][d]
    for (int r = 0; r < 16; ++r) {
        const int sl = w * 16 + r;
        const f16* p = QKVh + (size_t)(b * S_ + s0 + sl) * 3072 + 2560 + kv * HD_;
        const int d0 = lane * 2;
        half2v lo = *(const half2v*)(p + d0);
        half2v hi = *(const half2v*)(p + 128 + d0);
        float x0 = (float)lo[0], x1 = (float)lo[1], x2 = (float)hi[0], x3 = (float)hi[1];
        float ss = x0 * x0 + x1 * x1 + x2 * x2 + x3 * x3;
#pragma unroll
        for (int off = 32; off >= 1; off >>= 1) ss += __shfl_xor(ss, off);
        const float inv = rsqrtf(ss * (1.0f / HD_) + EPS_);
        half2v olo = {(f16)(x0 * inv), (f16)(x1 * inv)};
        half2v ohi = {(f16)(x2 * inv), (f16)(x3 * inv)};
        *(half2v*)&vt[sl][d0] = olo;
        *(half2v*)&vt[sl][128 + d0] = ohi;
    }
    __syncthreads();
    // phase 2: coalesced transposed write: wave w handles d-rows 64w..64w+63
    f16* dst = Vt + (size_t)(b * KV_ + kv) * HD_ * S_;
    for (int i = 0; i < 64; ++i) {
        const int dd = w * 64 + i;
        dst[(size_t)dd * S_ + s0 + lane] = vt[lane][dd];
    }
}

// ---------------------------------------------------------------------------
// MFMA flash attention (round-4 known-good). Block = (qt, h, b): 128 queries,
// 8 waves x 16 q. Double-buffered K/V LDS staging; one barrier per K-tile.
// __launch_bounds__(512,2): VGPR cap 256 — accumulators fit, NO spills.
// (Round-5 lesson: (512,4) capped the unified VGPR file at 64+64 and spilled
//  ~400 MB/dispatch to scratch — 2x regression.)
// ---------------------------------------------------------------------------
__global__ __launch_bounds__(512, 2) void attn_mfma(const f16* __restrict__ QKVh,
                                                    const f16* __restrict__ Kh,
                                                    const f16* __restrict__ Vt,
                                                    f16* __restrict__ attnh) {
    __shared__ __align__(16) f16 sK[2][64 * 256];  // [key][dim], XOR swizzle
    __shared__ __align__(16) f16 sV[2][256 * 64];  // [dim][key], XOR swizzle
    __shared__ __align__(16) f16 sP[8][16 * 72];   // per-wave P, stride 72

    const int qt = blockIdx.x, h = blockIdx.y, b = blockIdx.z;
    const int kvh = h / (H_ / KV_);
    const int t = threadIdx.x, lane = t & 63, w = t >> 6;
    const int i16 = lane & 15, q4 = lane >> 4;

    // Q fragments (A-layout): query row = i16, dims k = kk*32 + q4*8 + j
    const int qrow = qt * 128 + w * 16 + i16;
    const f16* qbase = QKVh + (size_t)(b * S_ + qrow) * 3072 + h * HD_ + q4 * 8;
    half8 qf[8];
#pragma unroll
    for (int kk = 0; kk < 8; ++kk) qf[kk] = *(const half8*)(qbase + kk * 32);

    floatx4 o[16];
#pragma unroll
    for (int i = 0; i < 16; ++i) o[i] = (floatx4){0.f, 0.f, 0.f, 0.f};
    float mrow[4] = {-1e30f, -1e30f, -1e30f, -1e30f};
    float lrow[4] = {0.f, 0.f, 0.f, 0.f};

    const size_t kbase = (size_t)(b * KV_ + kvh) * S_ * HD_;
    const size_t vbase = (size_t)(b * KV_ + kvh) * HD_ * S_;
    const int srow0 = qt * 128 + w * 16 + q4 * 4;

    // block-level and wave-level kt ranges (kt_lo = 2qt-8: first in-window
    // key for s=128qt is 128qt-511, in tile (128qt-511)>>6 = 2qt-8)
    const int kt_lo = (2 * qt - 8) > 0 ? (2 * qt - 8) : 0;
    const int kt_hi = 2 * qt + 1;
    const int s_lo_w = qt * 128 + w * 16;
    int ktw_lo = (s_lo_w - (WINDOW_ - 1)) >> 6;
    if (ktw_lo < kt_lo) ktw_lo = kt_lo;
    const int ktw_hi = (s_lo_w + 15) >> 6;

    auto stage = [&](int kt, int buf) {
#pragma unroll
        for (int c = 0; c < 4; ++c) {
            const int chunk = w * 4 + c;
            const int keyl = chunk * 2 + (lane >> 5);
            const int g = (lane & 31) ^ (keyl & 31);
            GLOAD_LDS16(Kh + kbase + (size_t)(kt * 64 + keyl) * HD_ + g * 8,
                        sK[buf] + chunk * 512 + lane * 8);
            const int diml = chunk * 8 + (lane >> 3);
            const int g2 = (lane & 7) ^ (diml & 7);
            GLOAD_LDS16(Vt + vbase + (size_t)diml * S_ + kt * 64 + g2 * 8,
                        sV[buf] + chunk * 512 + lane * 8);
        }
    };

    stage(kt_lo, 0);
    int cur = 0;
    for (int kt = kt_lo; kt <= kt_hi; ++kt, cur ^= 1) {
        __syncthreads();  // drains this wave's loads for buf `cur`, syncs all
        if (kt < kt_hi) stage(kt + 1, cur ^ 1);
        if (kt < ktw_lo || kt > ktw_hi) continue;

        const f16* sKc = sK[cur];
        const f16* sVc = sV[cur];

        // ---- QK^T: scores[16q x 64k] per wave ----
        floatx4 sc[4];
#pragma unroll
        for (int nt = 0; nt < 4; ++nt) sc[nt] = (floatx4){0.f, 0.f, 0.f, 0.f};
#pragma unroll
        for (int ks = 0; ks < 8; ++ks)
#pragma unroll
            for (int nt = 0; nt < 4; ++nt) {
                const int keyl = nt * 16 + i16;
                const int gp = (ks * 4 + q4) ^ (keyl & 31);
                half8 kf = *(const half8*)(sKc + keyl * 256 + gp * 8);
                sc[nt] = __builtin_amdgcn_mfma_f32_16x16x32_f16(qf[ks], kf, sc[nt], 0, 0, 0);
            }

        // ---- mask + online softmax ----
#pragma unroll
        for (int r = 0; r < 4; ++r) {
            const int s = srow0 + r;
            float mx = -1e30f;
#pragma unroll
            for (int nt = 0; nt < 4; ++nt) {
                const int j = kt * 64 + nt * 16 + i16;
                const bool valid = (j <= s) && (s - j < WINDOW_);
                const float v = valid ? sc[nt][r] : MASKV_;
                sc[nt][r] = v;
                mx = fmaxf(mx, v);
            }
#pragma unroll
            for (int off = 1; off < 16; off <<= 1) mx = fmaxf(mx, __shfl_xor(mx, off));
            const float mnew = fmaxf(mrow[r], mx);
            const float alpha = __expf(mrow[r] - mnew);
            mrow[r] = mnew;
            float rs = 0.f;
#pragma unroll
            for (int nt = 0; nt < 4; ++nt) {
                const float p = __expf(sc[nt][r] - mnew);
                sc[nt][r] = p;
                rs += p;
            }
#pragma unroll
            for (int off = 1; off < 16; off <<= 1) rs += __shfl_xor(rs, off);
            lrow[r] = lrow[r] * alpha + rs;
#pragma unroll
            for (int nt2 = 0; nt2 < 16; ++nt2) o[nt2][r] *= alpha;
        }

        // ---- P: C-layout -> LDS -> A-layout (wave-local) ----
        f16* sPw = sP[w];
#pragma unroll
        for (int nt = 0; nt < 4; ++nt)
#pragma unroll
            for (int r = 0; r < 4; ++r)
                sPw[(q4 * 4 + r) * 72 + nt * 16 + i16] = (f16)sc[nt][r];
        asm volatile("s_waitcnt lgkmcnt(0)" ::: "memory");

        // ---- PV: o[16q x 256d] += P[16q x 64k] @ V[64k x 256d] ----
#pragma unroll
        for (int kt2 = 0; kt2 < 2; ++kt2) {
            half8 pf = *(const half8*)(sPw + i16 * 72 + kt2 * 32 + q4 * 8);
#pragma unroll
            for (int nt2 = 0; nt2 < 16; ++nt2) {
                const int dim = nt2 * 16 + i16;
                const int gp = (kt2 * 4 + q4) ^ (dim & 7);
                half8 vf = *(const half8*)(sVc + dim * 64 + gp * 8);
                o[nt2] = __builtin_amdgcn_mfma_f32_16x16x32_f16(pf, vf, o[nt2], 0, 0, 0);
            }
        }
    }

    // ---- epilogue ----
    float inv[4];
#pragma unroll
    for (int r = 0; r < 4; ++r) inv[r] = 1.0f / lrow[r];
    f16* ob = attnh + (size_t)(b * S_ + qt * 128 + w * 16) * (H_ * HD_) + h * HD_;
#pragma unroll
    for (int nt2 = 0; nt2 < 16; ++nt2)
#pragma unroll
        for (int r = 0; r < 4; ++r)
            ob[(size_t)(q4 * 4 + r) * (H_ * HD_) + nt2 * 16 + i16] =
                (f16)(o[nt2][r] * inv[r]);
}

// ---------------------------------------------------------------------------
extern "C" void kernel_launch(void* const* d_in, const int* in_sizes, int n_in,
                              void* d_out, int out_size, void* d_ws, size_t ws_size,
                              hipStream_t stream) {
    const float* x    = (const float*)d_in[0];
    const float* cosb = (const float*)d_in[1];
    const float* sinb = (const float*)d_in[2];
    const float* wq = (const float*)d_in[4];
    const float* wk = (const float*)d_in[5];
    const float* wv = (const float*)d_in[6];
    const float* wo = (const float*)d_in[7];
    const float* qw = (const float*)d_in[8];
    const float* kw = (const float*)d_in[9];
    float* out = (float*)d_out;

    f16* ws = (f16*)d_ws;
    f16* xh    = ws;                       // 8388608 (aliased as attnh later)
    f16* BT    = xh + 8388608;             // 6291456  [3072][2048]
    f16* woT   = BT + 6291456;             // 4194304  [2048][2048]
    f16* QKVh  = woT + 4194304;            // 12582912 [4096][3072]
    f16* Kh    = QKVh + 12582912;          // 2097152
    f16* Vt    = Kh + 2097152;             // 2097152
    f16* attnh = xh;                       // alias: xh dead after QKV GEMM

    const int M = B_ * S_;  // 4096

    // 1) convert x + transpose all weights (one dispatch)
    prep<<<18432, 256, 0, stream>>>(x, wq, wk, wv, wo, xh, BT, woT);

    // 2) fused QKV projection: [4096][2048] @ [3072][2048]^T
    gemm_f16<f16><<<dim3(24, 32), 256, 0, stream>>>(xh, BT, QKVh, M, 3072, D_);

    // 3) RMSNorm + RoPE (Q,K) + V norm/coalesced-transpose (one dispatch)
    norm_rope_f16<<<NRB_ + 128, 256, 0, stream>>>(QKVh, Kh, Vt, cosb, sinb, qw, kw);

    // 4) flash attention (128-query tiles, double-buffered staging)
    attn_mfma<<<dim3(S_ / 128, H_, B_), 512, 0, stream>>>(QKVh, Kh, Vt, attnh);

    // 5) output projection (fp32 out)
    gemm_f16<float><<<dim3(16, 32), 256, 0, stream>>>(attnh, woT, out, M, D_, H_ * HD_);
}

// Round 7
// 325.226 us; speedup vs baseline: 1.3176x; 1.0428x over previous
//
#include <hip/hip_runtime.h>
#include <hip/hip_bf16.h>
#include <hip/hip_fp16.h>

#define B_ 2
#define S_ 2048
#define D_ 2048
#define H_ 8
#define KV_ 2
#define HD_ 256
#define WINDOW_ 512
#define EPS_ 1e-6f
#define MASKV_ -30000.0f

typedef _Float16 f16;
typedef _Float16 half8 __attribute__((ext_vector_type(8)));
typedef _Float16 half2v __attribute__((ext_vector_type(2)));
typedef _Float16 half4v __attribute__((ext_vector_type(4)));
typedef float floatx4 __attribute__((ext_vector_type(4)));
typedef float floatx8 __attribute__((ext_vector_type(8)));

#define GLOAD_LDS16(g, l)                                                        \
    __builtin_amdgcn_global_load_lds(                                            \
        (const __attribute__((address_space(1))) unsigned int*)(g),              \
        (__attribute__((address_space(3))) unsigned int*)(l), 16, 0, 0)

// ---------------------------------------------------------------------------
// prep: fp32->fp16 convert of x + all 4 weight transposes (64x64 tiles,
// half4 dst writes -> 128B contiguous store segments).
// blocks: [0,8192) x-convert; [8192,+1024) wq; [+256) wk; [+256) wv; [+1024) wo
// ---------------------------------------------------------------------------
__global__ __launch_bounds__(256) void prep(const float* __restrict__ x,
                                            const float* __restrict__ wq,
                                            const float* __restrict__ wk,
                                            const float* __restrict__ wv,
                                            const float* __restrict__ wo,
                                            f16* __restrict__ xh,
                                            f16* __restrict__ BT,
                                            f16* __restrict__ woT) {
    int bid = blockIdx.x;
    const int t = threadIdx.x;
    if (bid < 8192) {
        const int i = bid * 256 + t;
        float4 v = ((const float4*)x)[i];
        half4v hv = {(f16)v.x, (f16)v.y, (f16)v.z, (f16)v.w};
        ((half4v*)xh)[i] = hv;
        return;
    }
    bid -= 8192;
    const float* src;
    f16* dst;
    int C, bx, by;
    if (bid < 1024) {
        src = wq; dst = BT; C = 2048; bx = bid & 31; by = bid >> 5;
    } else if (bid < 1280) {
        const int b3 = bid - 1024;
        src = wk; dst = BT + (size_t)2048 * 2048; C = 512; bx = b3 & 7; by = b3 >> 3;
    } else if (bid < 1536) {
        const int b3 = bid - 1280;
        src = wv; dst = BT + (size_t)2560 * 2048; C = 512; bx = b3 & 7; by = b3 >> 3;
    } else {
        const int b3 = bid - 1536;
        src = wo; dst = woT; C = 2048; bx = b3 & 31; by = b3 >> 5;
    }
    __shared__ float tl[64][65];
    const int c0 = bx * 64, r0 = by * 64;
#pragma unroll
    for (int i = 0; i < 4; ++i) {
        const int idx = i * 256 + t;
        const int row = idx >> 4;
        const int c4 = (idx & 15) * 4;
        float4 v = *(const float4*)&src[(size_t)(r0 + row) * C + c0 + c4];
        tl[row][c4 + 0] = v.x; tl[row][c4 + 1] = v.y;
        tl[row][c4 + 2] = v.z; tl[row][c4 + 3] = v.w;
    }
    __syncthreads();
#pragma unroll
    for (int i = 0; i < 4; ++i) {
        const int idx = i * 256 + t;
        const int c = idx >> 4;
        const int r4 = (idx & 15) * 4;
        half4v hv = {(f16)tl[r4 + 0][c], (f16)tl[r4 + 1][c],
                     (f16)tl[r4 + 2][c], (f16)tl[r4 + 3][c]};
        *(half4v*)&dst[(size_t)(c0 + c) * 2048 + r0 + r4] = hv;
    }
}

// ---------------------------------------------------------------------------
// fp16 MFMA GEMM: C[M,N] = A[M,K] @ BT[N,K]^T.  128x128 tile, BK=64 (halves
// barrier-drain count vs BK=32; 32 KB LDS keeps grid-limited occupancy).
// Staging swizzle: LDS slot (chunk, r8=lane>>3, pos=lane&7) holds k-group
// g = pos ^ r8 of row chunk*8+r8. Fragment read of k-group G for row r is at
// pos = G ^ (r&7) -> 2-way max bank aliasing (free).
// ---------------------------------------------------------------------------
template <typename OutT>
__global__ __launch_bounds__(256) void gemm_f16(const f16* __restrict__ A,
                                                const f16* __restrict__ BT,
                                                OutT* __restrict__ C,
                                                int M, int N, int K) {
    __shared__ __align__(16) f16 sA[128 * 64];  // 16 KB
    __shared__ __align__(16) f16 sB[128 * 64];  // 16 KB

    const int t = threadIdx.x;
    const int lane = t & 63;
    const int w = t >> 6;
    const int i16 = lane & 15, q4 = lane >> 4;
    const int m0 = blockIdx.y * 128, n0 = blockIdx.x * 128;
    const int mw = (w & 1) * 64, nw = (w >> 1) * 64;

    floatx4 acc[16];
#pragma unroll
    for (int i = 0; i < 16; ++i) acc[i] = (floatx4){0.f, 0.f, 0.f, 0.f};

    const int r8 = lane >> 3;          // 0..7
    const int g = (lane & 7) ^ r8;     // staging k-group

    for (int k0 = 0; k0 < K; k0 += 64) {
#pragma unroll
        for (int cc = 0; cc < 4; ++cc) {
            const int chunk = w * 4 + cc;          // 0..15
            const int row = chunk * 8 + r8;        // 0..127
            GLOAD_LDS16(A + (size_t)(m0 + row) * K + k0 + g * 8,
                        sA + chunk * 512 + lane * 8);
            GLOAD_LDS16(BT + (size_t)(n0 + row) * K + k0 + g * 8,
                        sB + chunk * 512 + lane * 8);
        }
        __syncthreads();

        half8 af[2][4], bf[2][4];
#pragma unroll
        for (int kb = 0; kb < 2; ++kb)
#pragma unroll
            for (int mi = 0; mi < 4; ++mi) {
                const int ra = mw + mi * 16 + i16;
                const int ga = (kb * 4 + q4) ^ (ra & 7);
                af[kb][mi] = *(const half8*)(sA + (ra >> 3) * 512 + (ra & 7) * 64 + ga * 8);
                const int rb = nw + mi * 16 + i16;
                const int gb = (kb * 4 + q4) ^ (rb & 7);
                bf[kb][mi] = *(const half8*)(sB + (rb >> 3) * 512 + (rb & 7) * 64 + gb * 8);
            }
#pragma unroll
        for (int mi = 0; mi < 4; ++mi)
#pragma unroll
            for (int ni = 0; ni < 4; ++ni) {
                acc[mi * 4 + ni] = __builtin_amdgcn_mfma_f32_16x16x32_f16(
                    af[0][mi], bf[0][ni], acc[mi * 4 + ni], 0, 0, 0);
                acc[mi * 4 + ni] = __builtin_amdgcn_mfma_f32_16x16x32_f16(
                    af[1][mi], bf[1][ni], acc[mi * 4 + ni], 0, 0, 0);
            }
        __syncthreads();
    }

#pragma unroll
    for (int mi = 0; mi < 4; ++mi)
#pragma unroll
        for (int ni = 0; ni < 4; ++ni)
#pragma unroll
            for (int r = 0; r < 4; ++r) {
                const int row = m0 + mw + mi * 16 + q4 * 4 + r;
                const int col = n0 + nw + ni * 16 + i16;
                C[(size_t)row * N + col] = (OutT)acc[mi * 4 + ni][r];
            }
}

// ---------------------------------------------------------------------------
// K/V norm kernel (Q handled in attn prologue now).
// Blocks [0, NRBK_): K rows -> Kh (norm + rope). Blocks [NRBK_, +128): V norm
// + coalesced transpose to Vt via padded LDS tile.
// ---------------------------------------------------------------------------
#define NRBK_ ((B_ * S_ * KV_) / 4)  // 2048 blocks, 4 waves each

__global__ __launch_bounds__(256) void norm_kv_f16(
    const f16* __restrict__ QKVh, f16* __restrict__ Kh, f16* __restrict__ Vt,
    const float* __restrict__ cosb, const float* __restrict__ sinb,
    const float* __restrict__ kw) {
    __shared__ f16 vt[64][266];

    const int w = threadIdx.x >> 6, lane = threadIdx.x & 63;

    if (blockIdx.x < NRBK_) {
        const int wid = blockIdx.x * 4 + w;   // 0..8191
        const int d0 = lane * 2;
        const int b = wid / (S_ * KV_);
        const int r = wid % (S_ * KV_);
        const int s = r / KV_, kv = r % KV_;
        const f16* p = QKVh + (size_t)(b * S_ + s) * 3072 + 2048 + kv * HD_;
        half2v lo = *(const half2v*)(p + d0);
        half2v hi = *(const half2v*)(p + 128 + d0);
        float x0 = (float)lo[0], x1 = (float)lo[1], x2 = (float)hi[0], x3 = (float)hi[1];
        float ss = x0 * x0 + x1 * x1 + x2 * x2 + x3 * x3;
#pragma unroll
        for (int off = 32; off >= 1; off >>= 1) ss += __shfl_xor(ss, off);
        const float inv = rsqrtf(ss * (1.0f / HD_) + EPS_);
        float2 wlo = *(const float2*)(kw + d0), whi = *(const float2*)(kw + 128 + d0);
        float y0 = x0 * inv * wlo.x, y1 = x1 * inv * wlo.y;
        float y2 = x2 * inv * whi.x, y3 = x3 * inv * whi.y;
        const float* cb = cosb + (size_t)(b * S_ + s) * HD_;
        const float* sb = sinb + (size_t)(b * S_ + s) * HD_;
        float2 clo = *(const float2*)(cb + d0), chi = *(const float2*)(cb + 128 + d0);
        float2 slo = *(const float2*)(sb + d0), shi = *(const float2*)(sb + 128 + d0);
        half2v olo = {(f16)(y0 * clo.x - y2 * slo.x), (f16)(y1 * clo.y - y3 * slo.y)};
        half2v ohi = {(f16)(y2 * chi.x + y0 * shi.x), (f16)(y3 * chi.y + y1 * shi.y)};
        f16* d = Kh + ((size_t)(b * KV_ + kv) * S_ + s) * HD_;
        *(half2v*)(d + d0) = olo;
        *(half2v*)(d + 128 + d0) = ohi;
        return;
    }

    // ---- V path: one block per (b, kv, 64-row s-tile) ----
    const int vb = blockIdx.x - NRBK_;         // 0..127
    const int s0 = (vb & 31) * 64;
    const int kv = (vb >> 5) & 1;
    const int b  = vb >> 6;

    for (int r = 0; r < 16; ++r) {
        const int sl = w * 16 + r;
        const f16* p = QKVh + (size_t)(b * S_ + s0 + sl) * 3072 + 2560 + kv * HD_;
        const int d0 = lane * 2;
        half2v lo = *(const half2v*)(p + d0);
        half2v hi = *(const half2v*)(p + 128 + d0);
        float x0 = (float)lo[0], x1 = (float)lo[1], x2 = (float)hi[0], x3 = (float)hi[1];
        float ss = x0 * x0 + x1 * x1 + x2 * x2 + x3 * x3;
#pragma unroll
        for (int off = 32; off >= 1; off >>= 1) ss += __shfl_xor(ss, off);
        const float inv = rsqrtf(ss * (1.0f / HD_) + EPS_);
        half2v olo = {(f16)(x0 * inv), (f16)(x1 * inv)};
        half2v ohi = {(f16)(x2 * inv), (f16)(x3 * inv)};
        *(half2v*)&vt[sl][d0] = olo;
        *(half2v*)&vt[sl][128 + d0] = ohi;
    }
    __syncthreads();
    f16* dst = Vt + (size_t)(b * KV_ + kv) * HD_ * S_;
    for (int i = 0; i < 64; ++i) {
        const int dd = w * 64 + i;
        dst[(size_t)dd * S_ + s0 + lane] = vt[lane][dd];
    }
}

// ---------------------------------------------------------------------------
// MFMA flash attention. Block = (qt, h, b): 128 queries, 8 waves x 16 q.
// Double-buffered K/V LDS staging; one barrier per K-tile.
// Q RMSNorm+RoPE fused into the prologue: in A-layout, dim d and d+128 are in
// the SAME lane (qf[kk] <-> qf[kk+4]); row-SS = 2 shfl_xor across q4 groups.
// __launch_bounds__(512,2): VGPR cap 256 — no spills (round-5 lesson: (512,4)
// capped the unified file at 64+64 and spilled ~400MB/dispatch to scratch).
// ---------------------------------------------------------------------------
__global__ __launch_bounds__(512, 2) void attn_mfma(const f16* __restrict__ QKVh,
                                                    const f16* __restrict__ Kh,
                                                    const f16* __restrict__ Vt,
                                                    f16* __restrict__ attnh,
                                                    const float* __restrict__ cosb,
                                                    const float* __restrict__ sinb,
                                                    const float* __restrict__ qw) {
    __shared__ __align__(16) f16 sK[2][64 * 256];  // [key][dim], XOR swizzle
    __shared__ __align__(16) f16 sV[2][256 * 64];  // [dim][key], XOR swizzle
    __shared__ __align__(16) f16 sP[8][16 * 72];   // per-wave P, stride 72

    const int qt = blockIdx.x, h = blockIdx.y, b = blockIdx.z;
    const int kvh = h / (H_ / KV_);
    const int t = threadIdx.x, lane = t & 63, w = t >> 6;
    const int i16 = lane & 15, q4 = lane >> 4;

    // ---- load raw Q fragments (A-layout): row = i16, dim = kk*32 + q4*8 + j
    const int qrow = qt * 128 + w * 16 + i16;
    const f16* qbase = QKVh + (size_t)(b * S_ + qrow) * 3072 + h * HD_ + q4 * 8;
    half8 qf[8];
#pragma unroll
    for (int kk = 0; kk < 8; ++kk) qf[kk] = *(const half8*)(qbase + kk * 32);

    // ---- fused Q RMSNorm + RoPE (fp32 in-register) ----
    {
        float ss = 0.f;
#pragma unroll
        for (int kk = 0; kk < 8; ++kk)
#pragma unroll
            for (int j = 0; j < 8; ++j) {
                const float v = (float)qf[kk][j];
                ss += v * v;
            }
        ss += __shfl_xor(ss, 16);
        ss += __shfl_xor(ss, 32);
        const float inv = rsqrtf(ss * (1.0f / HD_) + EPS_);
        const float* cb = cosb + (size_t)(b * S_ + qrow) * HD_ + q4 * 8;
        const float* sb = sinb + (size_t)(b * S_ + qrow) * HD_ + q4 * 8;
        const float* wp = qw + q4 * 8;
#pragma unroll
        for (int kk = 0; kk < 4; ++kk) {
            const int dl = kk * 32, dh = dl + 128;
            floatx8 cl = *(const floatx8*)(cb + dl);
            floatx8 ch = *(const floatx8*)(cb + dh);
            floatx8 sl = *(const floatx8*)(sb + dl);
            floatx8 sh = *(const floatx8*)(sb + dh);
            floatx8 wl = *(const floatx8*)(wp + dl);
            floatx8 wh = *(const floatx8*)(wp + dh);
            half8 nl, nh;
#pragma unroll
            for (int j = 0; j < 8; ++j) {
                const float xl = (float)qf[kk][j] * inv * wl[j];
                const float xh = (float)qf[kk + 4][j] * inv * wh[j];
                nl[j] = (f16)(xl * cl[j] - xh * sl[j]);
                nh[j] = (f16)(xh * ch[j] + xl * sh[j]);
            }
            qf[kk] = nl;
            qf[kk + 4] = nh;
        }
    }

    floatx4 o[16];
#pragma unroll
    for (int i = 0; i < 16; ++i) o[i] = (floatx4){0.f, 0.f, 0.f, 0.f};
    float mrow[4] = {-1e30f, -1e30f, -1e30f, -1e30f};
    float lrow[4] = {0.f, 0.f, 0.f, 0.f};

    const size_t kbase = (size_t)(b * KV_ + kvh) * S_ * HD_;
    const size_t vbase = (size_t)(b * KV_ + kvh) * HD_ * S_;
    const int srow0 = qt * 128 + w * 16 + q4 * 4;

    const int kt_lo = (2 * qt - 8) > 0 ? (2 * qt - 8) : 0;
    const int kt_hi = 2 * qt + 1;
    const int s_lo_w = qt * 128 + w * 16;
    int ktw_lo = (s_lo_w - (WINDOW_ - 1)) >> 6;
    if (ktw_lo < kt_lo) ktw_lo = kt_lo;
    const int ktw_hi = (s_lo_w + 15) >> 6;

    auto stage = [&](int kt, int buf) {
#pragma unroll
        for (int c = 0; c < 4; ++c) {
            const int chunk = w * 4 + c;
            const int keyl = chunk * 2 + (lane >> 5);
            const int g = (lane & 31) ^ (keyl & 31);
            GLOAD_LDS16(Kh + kbase + (size_t)(kt * 64 + keyl) * HD_ + g * 8,
                        sK[buf] + chunk * 512 + lane * 8);
            const int diml = chunk * 8 + (lane >> 3);
            const int g2 = (lane & 7) ^ (diml & 7);
            GLOAD_LDS16(Vt + vbase + (size_t)diml * S_ + kt * 64 + g2 * 8,
                        sV[buf] + chunk * 512 + lane * 8);
        }
    };

    stage(kt_lo, 0);
    int cur = 0;
    for (int kt = kt_lo; kt <= kt_hi; ++kt, cur ^= 1) {
        __syncthreads();
        if (kt < kt_hi) stage(kt + 1, cur ^ 1);
        if (kt < ktw_lo || kt > ktw_hi) continue;

        const f16* sKc = sK[cur];
        const f16* sVc = sV[cur];

        floatx4 sc[4];
#pragma unroll
        for (int nt = 0; nt < 4; ++nt) sc[nt] = (floatx4){0.f, 0.f, 0.f, 0.f};
#pragma unroll
        for (int ks = 0; ks < 8; ++ks)
#pragma unroll
            for (int nt = 0; nt < 4; ++nt) {
                const int keyl = nt * 16 + i16;
                const int gp = (ks * 4 + q4) ^ (keyl & 31);
                half8 kf = *(const half8*)(sKc + keyl * 256 + gp * 8);
                sc[nt] = __builtin_amdgcn_mfma_f32_16x16x32_f16(qf[ks], kf, sc[nt], 0, 0, 0);
            }

#pragma unroll
        for (int r = 0; r < 4; ++r) {
            const int s = srow0 + r;
            float mx = -1e30f;
#pragma unroll
            for (int nt = 0; nt < 4; ++nt) {
                const int j = kt * 64 + nt * 16 + i16;
                const bool valid = (j <= s) && (s - j < WINDOW_);
                const float v = valid ? sc[nt][r] : MASKV_;
                sc[nt][r] = v;
                mx = fmaxf(mx, v);
            }
#pragma unroll
            for (int off = 1; off < 16; off <<= 1) mx = fmaxf(mx, __shfl_xor(mx, off));
            const float mnew = fmaxf(mrow[r], mx);
            const float alpha = __expf(mrow[r] - mnew);
            mrow[r] = mnew;
            float rs = 0.f;
#pragma unroll
            for (int nt = 0; nt < 4; ++nt) {
                const float p = __expf(sc[nt][r] - mnew);
                sc[nt][r] = p;
                rs += p;
            }
#pragma unroll
            for (int off = 1; off < 16; off <<= 1) rs += __shfl_xor(rs, off);
            lrow[r] = lrow[r] * alpha + rs;
#pragma unroll
            for (int nt2 = 0; nt2 < 16; ++nt2) o[nt2][r] *= alpha;
        }

        f16* sPw = sP[w];
#pragma unroll
        for (int nt = 0; nt < 4; ++nt)
#pragma unroll
            for (int r = 0; r < 4; ++r)
                sPw[(q4 * 4 + r) * 72 + nt * 16 + i16] = (f16)sc[nt][r];
        asm volatile("s_waitcnt lgkmcnt(0)" ::: "memory");

#pragma unroll
        for (int kt2 = 0; kt2 < 2; ++kt2) {
            half8 pf = *(const half8*)(sPw + i16 * 72 + kt2 * 32 + q4 * 8);
#pragma unroll
            for (int nt2 = 0; nt2 < 16; ++nt2) {
                const int dim = nt2 * 16 + i16;
                const int gp = (kt2 * 4 + q4) ^ (dim & 7);
                half8 vf = *(const half8*)(sVc + dim * 64 + gp * 8);
                o[nt2] = __builtin_amdgcn_mfma_f32_16x16x32_f16(pf, vf, o[nt2], 0, 0, 0);
            }
        }
    }

    float inv2[4];
#pragma unroll
    for (int r = 0; r < 4; ++r) inv2[r] = 1.0f / lrow[r];
    f16* ob = attnh + (size_t)(b * S_ + qt * 128 + w * 16) * (H_ * HD_) + h * HD_;
#pragma unroll
    for (int nt2 = 0; nt2 < 16; ++nt2)
#pragma unroll
        for (int r = 0; r < 4; ++r)
            ob[(size_t)(q4 * 4 + r) * (H_ * HD_) + nt2 * 16 + i16] =
                (f16)(o[nt2][r] * inv2[r]);
}

// ---------------------------------------------------------------------------
extern "C" void kernel_launch(void* const* d_in, const int* in_sizes, int n_in,
                              void* d_out, int out_size, void* d_ws, size_t ws_size,
                              hipStream_t stream) {
    const float* x    = (const float*)d_in[0];
    const float* cosb = (const float*)d_in[1];
    const float* sinb = (const float*)d_in[2];
    const float* wq = (const float*)d_in[4];
    const float* wk = (const float*)d_in[5];
    const float* wv = (const float*)d_in[6];
    const float* wo = (const float*)d_in[7];
    const float* qw = (const float*)d_in[8];
    const float* kw = (const float*)d_in[9];
    float* out = (float*)d_out;

    f16* ws = (f16*)d_ws;
    f16* xh    = ws;                       // 8388608 (aliased as attnh later)
    f16* BT    = xh + 8388608;             // 6291456  [3072][2048]
    f16* woT   = BT + 6291456;             // 4194304  [2048][2048]
    f16* QKVh  = woT + 4194304;            // 12582912 [4096][3072]
    f16* Kh    = QKVh + 12582912;          // 2097152
    f16* Vt    = Kh + 2097152;             // 2097152
    f16* attnh = xh;                       // alias: xh dead after QKV GEMM

    const int M = B_ * S_;  // 4096

    // 1) convert x + transpose all weights (one dispatch)
    prep<<<8192 + 2560, 256, 0, stream>>>(x, wq, wk, wv, wo, xh, BT, woT);

    // 2) fused QKV projection: [4096][2048] @ [3072][2048]^T  (BK=64)
    gemm_f16<f16><<<dim3(24, 32), 256, 0, stream>>>(xh, BT, QKVh, M, 3072, D_);

    // 3) K norm+rope -> Kh, V norm+transpose -> Vt (Q fused into attn)
    norm_kv_f16<<<NRBK_ + 128, 256, 0, stream>>>(QKVh, Kh, Vt, cosb, sinb, kw);

    // 4) flash attention (fused Q norm+rope, double-buffered staging)
    attn_mfma<<<dim3(S_ / 128, H_, B_), 512, 0, stream>>>(QKVh, Kh, Vt, attnh,
                                                          cosb, sinb, qw);

    // 5) output projection (fp32 out, BK=64)
    gemm_f16<float><<<dim3(16, 32), 256, 0, stream>>>(attnh, woT, out, M, D_, H_ * HD_);
}

// Round 8
// 310.817 us; speedup vs baseline: 1.3787x; 1.0464x over previous
//
#include <hip/hip_runtime.h>
#include <hip/hip_bf16.h>
#include <hip/hip_fp16.h>

#define B_ 2
#define S_ 2048
#define D_ 2048
#define H_ 8
#define KV_ 2
#define HD_ 256
#define WINDOW_ 512
#define EPS_ 1e-6f
#define MASKV_ -30000.0f

typedef _Float16 f16;
typedef _Float16 half8 __attribute__((ext_vector_type(8)));
typedef _Float16 half2v __attribute__((ext_vector_type(2)));
typedef _Float16 half4v __attribute__((ext_vector_type(4)));
typedef float floatx4 __attribute__((ext_vector_type(4)));
typedef float floatx8 __attribute__((ext_vector_type(8)));
typedef float floatx16 __attribute__((ext_vector_type(16)));

#define GLOAD_LDS16(g, l)                                                        \
    __builtin_amdgcn_global_load_lds(                                            \
        (const __attribute__((address_space(1))) unsigned int*)(g),              \
        (__attribute__((address_space(3))) unsigned int*)(l), 16, 0, 0)

// ---------------------------------------------------------------------------
// prep: fp32->fp16 convert of x + all 4 weight transposes (64x64 tiles,
// half4 dst writes -> 128B contiguous store segments).
// ---------------------------------------------------------------------------
__global__ __launch_bounds__(256) void prep(const float* __restrict__ x,
                                            const float* __restrict__ wq,
                                            const float* __restrict__ wk,
                                            const float* __restrict__ wv,
                                            const float* __restrict__ wo,
                                            f16* __restrict__ xh,
                                            f16* __restrict__ BT,
                                            f16* __restrict__ woT) {
    int bid = blockIdx.x;
    const int t = threadIdx.x;
    if (bid < 8192) {
        const int i = bid * 256 + t;
        float4 v = ((const float4*)x)[i];
        half4v hv = {(f16)v.x, (f16)v.y, (f16)v.z, (f16)v.w};
        ((half4v*)xh)[i] = hv;
        return;
    }
    bid -= 8192;
    const float* src;
    f16* dst;
    int C, bx, by;
    if (bid < 1024) {
        src = wq; dst = BT; C = 2048; bx = bid & 31; by = bid >> 5;
    } else if (bid < 1280) {
        const int b3 = bid - 1024;
        src = wk; dst = BT + (size_t)2048 * 2048; C = 512; bx = b3 & 7; by = b3 >> 3;
    } else if (bid < 1536) {
        const int b3 = bid - 1280;
        src = wv; dst = BT + (size_t)2560 * 2048; C = 512; bx = b3 & 7; by = b3 >> 3;
    } else {
        const int b3 = bid - 1536;
        src = wo; dst = woT; C = 2048; bx = b3 & 31; by = b3 >> 5;
    }
    __shared__ float tl[64][65];
    const int c0 = bx * 64, r0 = by * 64;
#pragma unroll
    for (int i = 0; i < 4; ++i) {
        const int idx = i * 256 + t;
        const int row = idx >> 4;
        const int c4 = (idx & 15) * 4;
        float4 v = *(const float4*)&src[(size_t)(r0 + row) * C + c0 + c4];
        tl[row][c4 + 0] = v.x; tl[row][c4 + 1] = v.y;
        tl[row][c4 + 2] = v.z; tl[row][c4 + 3] = v.w;
    }
    __syncthreads();
#pragma unroll
    for (int i = 0; i < 4; ++i) {
        const int idx = i * 256 + t;
        const int c = idx >> 4;
        const int r4 = (idx & 15) * 4;
        half4v hv = {(f16)tl[r4 + 0][c], (f16)tl[r4 + 1][c],
                     (f16)tl[r4 + 2][c], (f16)tl[r4 + 3][c]};
        *(half4v*)&dst[(size_t)(c0 + c) * 2048 + r0 + r4] = hv;
    }
}

// ---------------------------------------------------------------------------
// fp16 MFMA GEMM v2: C[M,N] = A[M,K] @ BT[N,K]^T.  128x128 tile, BK=64,
// 32x32x16 MFMA (2495 TF ceiling vs 2075 for 16x16x32; half the issue slots,
// half the LDS traffic per flop). Chunk stride 528 f16 (1056 B = 8 words mod
// 32) so 32-row fragment reads spread uniformly over banks (4 chunks x 8
// pos-slots -> bank-group (2c+pos)&7 is a permutation: minimum-cycle b128).
// A/B frag: m(n)=lane&31, k=(lane>>5)*8+j.  C/D: col=lane&31,
// row=(reg&3)+8*(reg>>2)+4*(lane>>5)  [m74/m101-verified].
// ---------------------------------------------------------------------------
#define CH_ 528  // chunk stride in f16
template <typename OutT>
__global__ __launch_bounds__(256) void gemm_f16(const f16* __restrict__ A,
                                                const f16* __restrict__ BT,
                                                OutT* __restrict__ C,
                                                int M, int N, int K) {
    __shared__ __align__(16) f16 sA[16 * CH_];  // 16.5 KB
    __shared__ __align__(16) f16 sB[16 * CH_];  // 16.5 KB

    const int t = threadIdx.x;
    const int lane = t & 63;
    const int w = t >> 6;
    const int l31 = lane & 31, q1 = lane >> 5;
    const int m0 = blockIdx.y * 128, n0 = blockIdx.x * 128;
    const int mw = (w & 1) * 64, nw = (w >> 1) * 64;

    floatx16 acc[4];
#pragma unroll
    for (int i = 0; i < 4; ++i) acc[i] = (floatx16)(0.f);

    const int r8 = lane >> 3;          // 0..7
    const int g = (lane & 7) ^ r8;     // staging k-group

    for (int k0 = 0; k0 < K; k0 += 64) {
#pragma unroll
        for (int cc = 0; cc < 4; ++cc) {
            const int chunk = w * 4 + cc;          // 0..15
            const int row = chunk * 8 + r8;        // 0..127
            GLOAD_LDS16(A + (size_t)(m0 + row) * K + k0 + g * 8,
                        sA + chunk * CH_ + lane * 8);
            GLOAD_LDS16(BT + (size_t)(n0 + row) * K + k0 + g * 8,
                        sB + chunk * CH_ + lane * 8);
        }
        __syncthreads();

#pragma unroll
        for (int ks = 0; ks < 4; ++ks) {
            const int G = ks * 2 + q1;
            half8 af[2], bf[2];
#pragma unroll
            for (int mt = 0; mt < 2; ++mt) {
                const int ra = mw + mt * 32 + l31;
                af[mt] = *(const half8*)(sA + (ra >> 3) * CH_ + (ra & 7) * 64 +
                                         (G ^ (ra & 7)) * 8);
                const int rb = nw + mt * 32 + l31;
                bf[mt] = *(const half8*)(sB + (rb >> 3) * CH_ + (rb & 7) * 64 +
                                         (G ^ (rb & 7)) * 8);
            }
#pragma unroll
            for (int mt = 0; mt < 2; ++mt)
#pragma unroll
                for (int nt = 0; nt < 2; ++nt)
                    acc[mt * 2 + nt] = __builtin_amdgcn_mfma_f32_32x32x16_f16(
                        af[mt], bf[nt], acc[mt * 2 + nt], 0, 0, 0);
        }
        __syncthreads();
    }

#pragma unroll
    for (int mt = 0; mt < 2; ++mt)
#pragma unroll
        for (int nt = 0; nt < 2; ++nt)
#pragma unroll
            for (int r = 0; r < 16; ++r) {
                const int row = m0 + mw + mt * 32 + (r & 3) + 8 * (r >> 2) + 4 * q1;
                const int col = n0 + nw + nt * 32 + l31;
                C[(size_t)row * N + col] = (OutT)acc[mt * 2 + nt][r];
            }
}

// ---------------------------------------------------------------------------
// K/V norm kernel (Q handled in attn prologue).
// ---------------------------------------------------------------------------
#define NRBK_ ((B_ * S_ * KV_) / 4)  // 2048 blocks, 4 waves each

__global__ __launch_bounds__(256) void norm_kv_f16(
    const f16* __restrict__ QKVh, f16* __restrict__ Kh, f16* __restrict__ Vt,
    const float* __restrict__ cosb, const float* __restrict__ sinb,
    const float* __restrict__ kw) {
    __shared__ f16 vt[64][266];

    const int w = threadIdx.x >> 6, lane = threadIdx.x & 63;

    if (blockIdx.x < NRBK_) {
        const int wid = blockIdx.x * 4 + w;   // 0..8191
        const int d0 = lane * 2;
        const int b = wid / (S_ * KV_);
        const int r = wid % (S_ * KV_);
        const int s = r / KV_, kv = r % KV_;
        const f16* p = QKVh + (size_t)(b * S_ + s) * 3072 + 2048 + kv * HD_;
        half2v lo = *(const half2v*)(p + d0);
        half2v hi = *(const half2v*)(p + 128 + d0);
        float x0 = (float)lo[0], x1 = (float)lo[1], x2 = (float)hi[0], x3 = (float)hi[1];
        float ss = x0 * x0 + x1 * x1 + x2 * x2 + x3 * x3;
#pragma unroll
        for (int off = 32; off >= 1; off >>= 1) ss += __shfl_xor(ss, off);
        const float inv = rsqrtf(ss * (1.0f / HD_) + EPS_);
        float2 wlo = *(const float2*)(kw + d0), whi = *(const float2*)(kw + 128 + d0);
        float y0 = x0 * inv * wlo.x, y1 = x1 * inv * wlo.y;
        float y2 = x2 * inv * whi.x, y3 = x3 * inv * whi.y;
        const float* cb = cosb + (size_t)(b * S_ + s) * HD_;
        const float* sb = sinb + (size_t)(b * S_ + s) * HD_;
        float2 clo = *(const float2*)(cb + d0), chi = *(const float2*)(cb + 128 + d0);
        float2 slo = *(const float2*)(sb + d0), shi = *(const float2*)(sb + 128 + d0);
        half2v olo = {(f16)(y0 * clo.x - y2 * slo.x), (f16)(y1 * clo.y - y3 * slo.y)};
        half2v ohi = {(f16)(y2 * chi.x + y0 * shi.x), (f16)(y3 * chi.y + y1 * shi.y)};
        f16* d = Kh + ((size_t)(b * KV_ + kv) * S_ + s) * HD_;
        *(half2v*)(d + d0) = olo;
        *(half2v*)(d + 128 + d0) = ohi;
        return;
    }

    const int vb = blockIdx.x - NRBK_;         // 0..127
    const int s0 = (vb & 31) * 64;
    const int kv = (vb >> 5) & 1;
    const int b  = vb >> 6;

    for (int r = 0; r < 16; ++r) {
        const int sl = w * 16 + r;
        const f16* p = QKVh + (size_t)(b * S_ + s0 + sl) * 3072 + 2560 + kv * HD_;
        const int d0 = lane * 2;
        half2v lo = *(const half2v*)(p + d0);
        half2v hi = *(const half2v*)(p + 128 + d0);
        float x0 = (float)lo[0], x1 = (float)lo[1], x2 = (float)hi[0], x3 = (float)hi[1];
        float ss = x0 * x0 + x1 * x1 + x2 * x2 + x3 * x3;
#pragma unroll
        for (int off = 32; off >= 1; off >>= 1) ss += __shfl_xor(ss, off);
        const float inv = rsqrtf(ss * (1.0f / HD_) + EPS_);
        half2v olo = {(f16)(x0 * inv), (f16)(x1 * inv)};
        half2v ohi = {(f16)(x2 * inv), (f16)(x3 * inv)};
        *(half2v*)&vt[sl][d0] = olo;
        *(half2v*)&vt[sl][128 + d0] = ohi;
    }
    __syncthreads();
    f16* dst = Vt + (size_t)(b * KV_ + kv) * HD_ * S_;
    for (int i = 0; i < 64; ++i) {
        const int dd = w * 64 + i;
        dst[(size_t)dd * S_ + s0 + lane] = vt[lane][dd];
    }
}

// ---------------------------------------------------------------------------
// MFMA flash attention (unchanged from round 7). 128 q, 8 waves, dbuf staging.
// ---------------------------------------------------------------------------
__global__ __launch_bounds__(512, 2) void attn_mfma(const f16* __restrict__ QKVh,
                                                    const f16* __restrict__ Kh,
                                                    const f16* __restrict__ Vt,
                                                    f16* __restrict__ attnh,
                                                    const float* __restrict__ cosb,
                                                    const float* __restrict__ sinb,
                                                    const float* __restrict__ qw) {
    __shared__ __align__(16) f16 sK[2][64 * 256];
    __shared__ __align__(16) f16 sV[2][256 * 64];
    __shared__ __align__(16) f16 sP[8][16 * 72];

    const int qt = blockIdx.x, h = blockIdx.y, b = blockIdx.z;
    const int kvh = h / (H_ / KV_);
    const int t = threadIdx.x, lane = t & 63, w = t >> 6;
    const int i16 = lane & 15, q4 = lane >> 4;

    const int qrow = qt * 128 + w * 16 + i16;
    const f16* qbase = QKVh + (size_t)(b * S_ + qrow) * 3072 + h * HD_ + q4 * 8;
    half8 qf[8];
#pragma unroll
    for (int kk = 0; kk < 8; ++kk) qf[kk] = *(const half8*)(qbase + kk * 32);

    {
        float ss = 0.f;
#pragma unroll
        for (int kk = 0; kk < 8; ++kk)
#pragma unroll
            for (int j = 0; j < 8; ++j) {
                const float v = (float)qf[kk][j];
                ss += v * v;
            }
        ss += __shfl_xor(ss, 16);
        ss += __shfl_xor(ss, 32);
        const float inv = rsqrtf(ss * (1.0f / HD_) + EPS_);
        const float* cb = cosb + (size_t)(b * S_ + qrow) * HD_ + q4 * 8;
        const float* sb = sinb + (size_t)(b * S_ + qrow) * HD_ + q4 * 8;
        const float* wp = qw + q4 * 8;
#pragma unroll
        for (int kk = 0; kk < 4; ++kk) {
            const int dl = kk * 32, dh = dl + 128;
            floatx8 cl = *(const floatx8*)(cb + dl);
            floatx8 ch = *(const floatx8*)(cb + dh);
            floatx8 sl = *(const floatx8*)(sb + dl);
            floatx8 sh = *(const floatx8*)(sb + dh);
            floatx8 wl = *(const floatx8*)(wp + dl);
            floatx8 wh = *(const floatx8*)(wp + dh);
            half8 nl, nh;
#pragma unroll
            for (int j = 0; j < 8; ++j) {
                const float xl = (float)qf[kk][j] * inv * wl[j];
                const float xh = (float)qf[kk + 4][j] * inv * wh[j];
                nl[j] = (f16)(xl * cl[j] - xh * sl[j]);
                nh[j] = (f16)(xh * ch[j] + xl * sh[j]);
            }
            qf[kk] = nl;
            qf[kk + 4] = nh;
        }
    }

    floatx4 o[16];
#pragma unroll
    for (int i = 0; i < 16; ++i) o[i] = (floatx4){0.f, 0.f, 0.f, 0.f};
    float mrow[4] = {-1e30f, -1e30f, -1e30f, -1e30f};
    float lrow[4] = {0.f, 0.f, 0.f, 0.f};

    const size_t kbase = (size_t)(b * KV_ + kvh) * S_ * HD_;
    const size_t vbase = (size_t)(b * KV_ + kvh) * HD_ * S_;
    const int srow0 = qt * 128 + w * 16 + q4 * 4;

    const int kt_lo = (2 * qt - 8) > 0 ? (2 * qt - 8) : 0;
    const int kt_hi = 2 * qt + 1;
    const int s_lo_w = qt * 128 + w * 16;
    int ktw_lo = (s_lo_w - (WINDOW_ - 1)) >> 6;
    if (ktw_lo < kt_lo) ktw_lo = kt_lo;
    const int ktw_hi = (s_lo_w + 15) >> 6;

    auto stage = [&](int kt, int buf) {
#pragma unroll
        for (int c = 0; c < 4; ++c) {
            const int chunk = w * 4 + c;
            const int keyl = chunk * 2 + (lane >> 5);
            const int g = (lane & 31) ^ (keyl & 31);
            GLOAD_LDS16(Kh + kbase + (size_t)(kt * 64 + keyl) * HD_ + g * 8,
                        sK[buf] + chunk * 512 + lane * 8);
            const int diml = chunk * 8 + (lane >> 3);
            const int g2 = (lane & 7) ^ (diml & 7);
            GLOAD_LDS16(Vt + vbase + (size_t)diml * S_ + kt * 64 + g2 * 8,
                        sV[buf] + chunk * 512 + lane * 8);
        }
    };

    stage(kt_lo, 0);
    int cur = 0;
    for (int kt = kt_lo; kt <= kt_hi; ++kt, cur ^= 1) {
        __syncthreads();
        if (kt < kt_hi) stage(kt + 1, cur ^ 1);
        if (kt < ktw_lo || kt > ktw_hi) continue;

        const f16* sKc = sK[cur];
        const f16* sVc = sV[cur];

        floatx4 sc[4];
#pragma unroll
        for (int nt = 0; nt < 4; ++nt) sc[nt] = (floatx4){0.f, 0.f, 0.f, 0.f};
#pragma unroll
        for (int ks = 0; ks < 8; ++ks)
#pragma unroll
            for (int nt = 0; nt < 4; ++nt) {
                const int keyl = nt * 16 + i16;
                const int gp = (ks * 4 + q4) ^ (keyl & 31);
                half8 kf = *(const half8*)(sKc + keyl * 256 + gp * 8);
                sc[nt] = __builtin_amdgcn_mfma_f32_16x16x32_f16(qf[ks], kf, sc[nt], 0, 0, 0);
            }

#pragma unroll
        for (int r = 0; r < 4; ++r) {
            const int s = srow0 + r;
            float mx = -1e30f;
#pragma unroll
            for (int nt = 0; nt < 4; ++nt) {
                const int j = kt * 64 + nt * 16 + i16;
                const bool valid = (j <= s) && (s - j < WINDOW_);
                const float v = valid ? sc[nt][r] : MASKV_;
                sc[nt][r] = v;
                mx = fmaxf(mx, v);
            }
#pragma unroll
            for (int off = 1; off < 16; off <<= 1) mx = fmaxf(mx, __shfl_xor(mx, off));
            const float mnew = fmaxf(mrow[r], mx);
            const float alpha = __expf(mrow[r] - mnew);
            mrow[r] = mnew;
            float rs = 0.f;
#pragma unroll
            for (int nt = 0; nt < 4; ++nt) {
                const float p = __expf(sc[nt][r] - mnew);
                sc[nt][r] = p;
                rs += p;
            }
#pragma unroll
            for (int off = 1; off < 16; off <<= 1) rs += __shfl_xor(rs, off);
            lrow[r] = lrow[r] * alpha + rs;
#pragma unroll
            for (int nt2 = 0; nt2 < 16; ++nt2) o[nt2][r] *= alpha;
        }

        f16* sPw = sP[w];
#pragma unroll
        for (int nt = 0; nt < 4; ++nt)
#pragma unroll
            for (int r = 0; r < 4; ++r)
                sPw[(q4 * 4 + r) * 72 + nt * 16 + i16] = (f16)sc[nt][r];
        asm volatile("s_waitcnt lgkmcnt(0)" ::: "memory");

#pragma unroll
        for (int kt2 = 0; kt2 < 2; ++kt2) {
            half8 pf = *(const half8*)(sPw + i16 * 72 + kt2 * 32 + q4 * 8);
#pragma unroll
            for (int nt2 = 0; nt2 < 16; ++nt2) {
                const int dim = nt2 * 16 + i16;
                const int gp = (kt2 * 4 + q4) ^ (dim & 7);
                half8 vf = *(const half8*)(sVc + dim * 64 + gp * 8);
                o[nt2] = __builtin_amdgcn_mfma_f32_16x16x32_f16(pf, vf, o[nt2], 0, 0, 0);
            }
        }
    }

    float inv2[4];
#pragma unroll
    for (int r = 0; r < 4; ++r) inv2[r] = 1.0f / lrow[r];
    f16* ob = attnh + (size_t)(b * S_ + qt * 128 + w * 16) * (H_ * HD_) + h * HD_;
#pragma unroll
    for (int nt2 = 0; nt2 < 16; ++nt2)
#pragma unroll
        for (int r = 0; r < 4; ++r)
            ob[(size_t)(q4 * 4 + r) * (H_ * HD_) + nt2 * 16 + i16] =
                (f16)(o[nt2][r] * inv2[r]);
}

// ---------------------------------------------------------------------------
extern "C" void kernel_launch(void* const* d_in, const int* in_sizes, int n_in,
                              void* d_out, int out_size, void* d_ws, size_t ws_size,
                              hipStream_t stream) {
    const float* x    = (const float*)d_in[0];
    const float* cosb = (const float*)d_in[1];
    const float* sinb = (const float*)d_in[2];
    const float* wq = (const float*)d_in[4];
    const float* wk = (const float*)d_in[5];
    const float* wv = (const float*)d_in[6];
    const float* wo = (const float*)d_in[7];
    const float* qw = (const float*)d_in[8];
    const float* kw = (const float*)d_in[9];
    float* out = (float*)d_out;

    f16* ws = (f16*)d_ws;
    f16* xh    = ws;                       // 8388608 (aliased as attnh later)
    f16* BT    = xh + 8388608;             // 6291456  [3072][2048]
    f16* woT   = BT + 6291456;             // 4194304  [2048][2048]
    f16* QKVh  = woT + 4194304;            // 12582912 [4096][3072]
    f16* Kh    = QKVh + 12582912;          // 2097152
    f16* Vt    = Kh + 2097152;             // 2097152
    f16* attnh = xh;                       // alias: xh dead after QKV GEMM

    const int M = B_ * S_;  // 4096

    // 1) convert x + transpose all weights (one dispatch)
    prep<<<8192 + 2560, 256, 0, stream>>>(x, wq, wk, wv, wo, xh, BT, woT);

    // 2) fused QKV projection: [4096][2048] @ [3072][2048]^T  (BK=64, 32x32x16)
    gemm_f16<f16><<<dim3(24, 32), 256, 0, stream>>>(xh, BT, QKVh, M, 3072, D_);

    // 3) K norm+rope -> Kh, V norm+transpose -> Vt (Q fused into attn)
    norm_kv_f16<<<NRBK_ + 128, 256, 0, stream>>>(QKVh, Kh, Vt, cosb, sinb, kw);

    // 4) flash attention (fused Q norm+rope, double-buffered staging)
    attn_mfma<<<dim3(S_ / 128, H_, B_), 512, 0, stream>>>(QKVh, Kh, Vt, attnh,
                                                          cosb, sinb, qw);

    // 5) output projection (fp32 out, BK=64, 32x32x16)
    gemm_f16<float><<<dim3(16, 32), 256, 0, stream>>>(attnh, woT, out, M, D_, H_ * HD_);
}